// Round 7
// baseline (108.681 us; speedup 1.0000x reference)
//
#include <hip/hip_runtime.h>

#define KK 40        // N_RADIAL * N_ANGULAR
#define M3 120       // KK * 3
#define MM4 30       // float4 chunks of bw/bi per vertex
#define RCH 15       // chunks per staging round
#define FEAT 16
#define NT 8
#define ODIM 32
#define VPB 64       // vertices per block
#define BLOCK 512
#define SST 17       // staged stream row stride (float4 units) — bank-spread

typedef unsigned int u32;
typedef unsigned short u16;
typedef float  f32x2 __attribute__((ext_vector_type(2)));
typedef float  f32x4 __attribute__((ext_vector_type(4)));
typedef int    i32x4 __attribute__((ext_vector_type(4)));
typedef u32    u32x4 __attribute__((ext_vector_type(4)));

// cs3[m] = csum[m/3], csum[k] = sum_{ra} ic[ra][k]
__global__ void cs3_kernel(const float* __restrict__ ic, float* __restrict__ cs3) {
    __shared__ float cs[KK];
    const int t = threadIdx.x;
    if (t < KK) {
        float s = 0.f;
        #pragma unroll
        for (int ra = 0; ra < KK; ++ra) s += ic[ra * KK + t];
        cs[t] = s;
    }
    __syncthreads();
    if (t < M3) cs3[t] = cs[t / 3];
}

__device__ __forceinline__ u16 f2bf_rne(float x) {
    u32 u = __float_as_uint(x);
    u32 r = (u + 0x7fffu + ((u >> 16) & 1u)) >> 16;   // round-to-nearest-even
    return (u16)r;
}

// mesh fp32 -> bf16, 8 elements per thread, non-temporal both ways
__global__ void cvt_kernel(const float* __restrict__ mesh, u16* __restrict__ mbf, int total) {
    const int i = blockIdx.x * blockDim.x + threadIdx.x;
    const int base = i * 8;
    if (base < total) {
        f32x4 a = __builtin_nontemporal_load((const f32x4*)(mesh + base));
        f32x4 b = __builtin_nontemporal_load((const f32x4*)(mesh + base + 4));
        u32x4 v;
        v.x = (u32)f2bf_rne(a.x) | ((u32)f2bf_rne(a.y) << 16);
        v.y = (u32)f2bf_rne(a.z) | ((u32)f2bf_rne(a.w) << 16);
        v.z = (u32)f2bf_rne(b.x) | ((u32)f2bf_rne(b.y) << 16);
        v.w = (u32)f2bf_rne(b.z) | ((u32)f2bf_rne(b.w) << 16);
        __builtin_nontemporal_store(v, (u32x4*)(mbf + base));
    }
}

// accumulate one gathered bf16x8 row-half (u32x4) scaled by s into acc2[0..3]
__device__ __forceinline__ void acc8(f32x2 acc2[4], const u32x4 g, const float s) {
    const f32x2 s2 = {s, s};
    f32x2 p;
    p.x = __uint_as_float(g.x << 16);
    p.y = __uint_as_float(g.x & 0xffff0000u);
    acc2[0] = __builtin_elementwise_fma(p, s2, acc2[0]);
    p.x = __uint_as_float(g.y << 16);
    p.y = __uint_as_float(g.y & 0xffff0000u);
    acc2[1] = __builtin_elementwise_fma(p, s2, acc2[1]);
    p.x = __uint_as_float(g.z << 16);
    p.y = __uint_as_float(g.z & 0xffff0000u);
    acc2[2] = __builtin_elementwise_fma(p, s2, acc2[2]);
    p.x = __uint_as_float(g.w << 16);
    p.y = __uint_as_float(g.w & 0xffff0000u);
    acc2[3] = __builtin_elementwise_fma(p, s2, acc2[3]);
}

__global__ __launch_bounds__(BLOCK, 8) void conv_kernel(
    const u16*   __restrict__ mbf,    // [N,16] bf16, L2-resident (3.2 MB)
    const float* __restrict__ bw,     // [N,120]
    const float* __restrict__ W,      // [8,32,16]
    const float* __restrict__ bias,   // [8,32]
    const int*   __restrict__ bi,     // [N,120]
    const float* __restrict__ cs3,    // [120]
    float*       __restrict__ out,    // [N,32]
    int n)
{
    // stream staging buffer (bw | bi), reused as s_out in phase 2/3
    __shared__ f32x4 s_buf[VPB * SST * 2];               // 34816 B
    __shared__ float s_sig[VPB][FEAT + 1];               //  4352 B

    f32x4* s_bw4 = s_buf;
    i32x4* s_bi4 = (i32x4*)(s_buf + VPB * SST);
    float (*s_out)[ODIM + 1] = (float(*)[ODIM + 1])s_buf;

    const int tid = threadIdx.x;
    const int vg0 = blockIdx.x * VPB;

    const f32x4* bw4g  = (const f32x4*)bw;
    const i32x4* bi4g  = (const i32x4*)bi;
    const f32x4* cs34g = (const f32x4*)cs3;

    // phase-1 lane mapping: tid = vloc*8 + jc*4 + mc*2 + q
    const int vloc = tid >> 3;
    const int jc   = (tid >> 2) & 1;
    const int mc   = (tid >> 1) & 1;
    const int q    = tid & 1;
    const int vg   = vg0 + vloc;

    f32x2 acc2[4];
    #pragma unroll
    for (int e = 0; e < 4; ++e) acc2[e] = (f32x2){0.f, 0.f};

    #pragma unroll
    for (int r = 0; r < 2; ++r) {
        if (r) __syncthreads();   // round-0 LDS reads done before restaging

        // ---- cooperative staging: each stream byte loaded exactly once ----
        #pragma unroll
        for (int ii = 0; ii < 2; ++ii) {
            const int i = tid + ii * BLOCK;
            if (i < VPB * RCH) {
                const int v = i / RCH;
                const int c = i - v * RCH;
                if (vg0 + v < n) {
                    const int gchunk = (vg0 + v) * MM4 + r * RCH + c;
                    f32x4 wv = __builtin_nontemporal_load(bw4g + gchunk);
                    i32x4 iv = __builtin_nontemporal_load(bi4g + gchunk);
                    const f32x4 cc = cs34g[r * RCH + c];
                    wv.x *= cc.x; wv.y *= cc.y; wv.z *= cc.z; wv.w *= cc.w;
                    s_bw4[v * SST + c] = wv;
                    s_bi4[v * SST + c] = iv;
                }
            }
        }
        __syncthreads();

        // ---- gather round: mc=0 -> chunks [0,8), mc=1 -> chunks [8,15) ----
        // batched 2 chunks (4 gathers in flight) per iteration
        if (vg < n) {
            const int cbase = mc ? 8 : 0;
            #pragma unroll
            for (int ib = 0; ib < 4; ++ib) {
                const int c0 = cbase + 2 * ib;
                const int c1 = c0 + 1;
                const bool has1 = !(mc && (ib == 3));   // mc=1 has 7 chunks

                const f32x4 wA = s_bw4[vloc * SST + c0];
                const i32x4 iA = s_bi4[vloc * SST + c0];
                const float wa0 = jc ? wA.z : wA.x;
                const float wa1 = jc ? wA.w : wA.y;
                const int   ia0 = jc ? iA.z : iA.x;
                const int   ia1 = jc ? iA.w : iA.y;
                const u32x4 gA0 = *((const u32x4*)(mbf + (size_t)ia0 * FEAT) + q);
                const u32x4 gA1 = *((const u32x4*)(mbf + (size_t)ia1 * FEAT) + q);

                if (has1) {
                    const f32x4 wB = s_bw4[vloc * SST + c1];
                    const i32x4 iB = s_bi4[vloc * SST + c1];
                    const float wb0 = jc ? wB.z : wB.x;
                    const float wb1 = jc ? wB.w : wB.y;
                    const int   ib0 = jc ? iB.z : iB.x;
                    const int   ib1 = jc ? iB.w : iB.y;
                    const u32x4 gB0 = *((const u32x4*)(mbf + (size_t)ib0 * FEAT) + q);
                    const u32x4 gB1 = *((const u32x4*)(mbf + (size_t)ib1 * FEAT) + q);
                    acc8(acc2, gA0, wa0);
                    acc8(acc2, gA1, wa1);
                    acc8(acc2, gB0, wb0);
                    acc8(acc2, gB1, wb1);
                } else {
                    acc8(acc2, gA0, wa0);
                    acc8(acc2, gA1, wa1);
                }
            }
        }
    }

    // ---- cross-lane reduce: jc (xor 4) then mc (xor 2) ----
    float a8[8] = { acc2[0].x, acc2[0].y, acc2[1].x, acc2[1].y,
                    acc2[2].x, acc2[2].y, acc2[3].x, acc2[3].y };
    #pragma unroll
    for (int e = 0; e < 8; ++e) a8[e] += __shfl_xor(a8[e], 4);
    #pragma unroll
    for (int e = 0; e < 8; ++e) a8[e] += __shfl_xor(a8[e], 2);

    if (jc == 0) {
        const f32x4 v = (mc == 0) ? (f32x4){a8[0], a8[1], a8[2], a8[3]}
                                  : (f32x4){a8[4], a8[5], a8[6], a8[7]};
        *(f32x4*)(&s_sig[vloc][q * 8 + mc * 4]) = v;
    }
    __syncthreads();   // s_sig ready; stream reads all done (s_buf reusable)

    // ---------------- Phase 2: fold (W @ s, relu, sum over t) ----------------
    // wave w (0..7) owns wave-uniform outputs [4w, 4w+4); lane = vertex (64).
    {
        const int lane = tid & 63;
        const int wave = __builtin_amdgcn_readfirstlane(tid >> 6);  // 0..7

        float s[FEAT];
        #pragma unroll
        for (int f = 0; f < FEAT; ++f) s[f] = s_sig[lane][f];

        float oacc[4];
        #pragma unroll
        for (int oi = 0; oi < 4; ++oi) oacc[oi] = 0.f;

        #pragma unroll 2
        for (int t = 0; t < NT; ++t) {
            #pragma unroll
            for (int oi = 0; oi < 4; ++oi) {
                const int o = wave * 4 + oi;
                float pre = bias[t * ODIM + o];                        // scalar load
                const float* wrow = W + ((size_t)t * ODIM + o) * FEAT; // scalar loads
                #pragma unroll
                for (int f = 0; f < FEAT; ++f)
                    pre = fmaf(wrow[f], s[f], pre);
                oacc[oi] += fmaxf(pre, 0.f);
            }
        }

        *(f32x4*)(&s_out[lane][wave * 4]) = (f32x4){oacc[0], oacc[1], oacc[2], oacc[3]};
    }
    __syncthreads();

    // ---------------- Phase 3: coalesced output write ----------------
    // 8 threads per vertex; each writes one float4 -> full 128B line/vertex.
    {
        const int v   = tid >> 3;
        const int oq  = tid & 7;
        const int vgo = vg0 + v;
        if (vgo < n) {
            const f32x4 val = { s_out[v][oq * 4 + 0], s_out[v][oq * 4 + 1],
                                s_out[v][oq * 4 + 2], s_out[v][oq * 4 + 3] };
            __builtin_nontemporal_store(val, (f32x4*)(out + (size_t)vgo * ODIM + oq * 4));
        }
    }
}

extern "C" void kernel_launch(void* const* d_in, const int* in_sizes, int n_in,
                              void* d_out, int out_size, void* d_ws, size_t ws_size,
                              hipStream_t stream) {
    const float* mesh = (const float*)d_in[0];
    const float* bw   = (const float*)d_in[1];
    const float* ic   = (const float*)d_in[2];
    const float* W    = (const float*)d_in[3];
    const float* bias = (const float*)d_in[4];
    const int*   bi   = (const int*)d_in[5];
    float* out = (float*)d_out;

    const int n = in_sizes[0] / FEAT;   // N_VERTS
    const int total = n * FEAT;

    // workspace layout: [0,512) cs3, [512, 512 + n*16*2) bf16 mesh
    float* cs3 = (float*)d_ws;
    u16*   mbf = (u16*)((char*)d_ws + 512);

    cs3_kernel<<<1, 128, 0, stream>>>(ic, cs3);

    const int cvt_threads = (total + 7) / 8;
    cvt_kernel<<<(cvt_threads + 255) / 256, 256, 0, stream>>>(mesh, mbf, total);

    const int blocks = (n + VPB - 1) / VPB;
    conv_kernel<<<blocks, BLOCK, 0, stream>>>(mbf, bw, W, bias, bi, cs3, out, n);
}